// Round 1
// 257.522 us; speedup vs baseline: 1.1888x; 1.1888x over previous
//
#include <hip/hip_runtime.h>
#include <stdint.h>

#define N_NODES_C 20000
#define N_EDGES_C 320000
#define NUM_RELS_C 16
#define FEAT_C 256

typedef __bf16 bf16_t;
typedef __bf16 bf16x8 __attribute__((ext_vector_type(8)));
typedef __bf16 bf16x4 __attribute__((ext_vector_type(4)));
typedef float f32x4 __attribute__((ext_vector_type(4)));

__device__ __forceinline__ void async_load16(const void* g, void* l) {
  __builtin_amdgcn_global_load_lds(
      (__attribute__((address_space(1))) void*)const_cast<void*>(g),
      (__attribute__((address_space(3))) void*)l, 16, 0, 0);
}

// ---- h fp32 -> bf16 ----
__global__ void cvt_h_kernel(const float* __restrict__ h, bf16_t* __restrict__ hB) {
  int i = (blockIdx.x * blockDim.x + threadIdx.x) * 4;
  float4 v = *(const float4*)(h + i);
  bf16x4 o = { (bf16_t)v.x, (bf16_t)v.y, (bf16_t)v.z, (bf16_t)v.w };
  *(bf16x4*)(hB + i) = o;
}

// ---- W [r][in][out] fp32 -> Wt [r][out][in] bf16 ----
__global__ void cvt_w_kernel(const float* __restrict__ W, bf16_t* __restrict__ Wt) {
  int g = blockIdx.x * blockDim.x + threadIdx.x;
  int i = g & 255;
  int o = (g >> 8) & 255;
  int r = g >> 16;
  Wt[(r << 16) + (o << 8) + i] = (bf16_t)W[(r << 16) + (i << 8) + o];
}

// ---- dst histogram (counts land in dcur) ----
__global__ void hist_dst_kernel(const int* __restrict__ dst, int* __restrict__ dcur) {
  int e = blockIdx.x * blockDim.x + threadIdx.x;
  if (e < N_EDGES_C) atomicAdd(&dcur[dst[e]], 1);
}

// ---- single-block exclusive scan over 20000 counts -> dstart[20001], dcur=start cursors ----
// Counts are staged in LDS (u16) in pass 1 so pass 2's run+=c chain is LDS-local,
// not a 79-deep dependent global-load chain. (Counts ~Poisson(16) << 65535.)
__global__ void scan_dst_kernel(int* __restrict__ dcur, int* __restrict__ dstart) {
  __shared__ unsigned short cnt[20224];  // 256*79, 40.4 KB
  __shared__ int part[256];
  const int CH = 79;  // 256*79 = 20224 >= 20000
  int t = threadIdx.x;
  int base = t * CH;
  int sum = 0;
  for (int i = 0; i < CH; ++i) {
    int idx = base + i;
    int c = (idx < N_NODES_C) ? dcur[idx] : 0;
    cnt[idx] = (unsigned short)c;
    sum += c;
  }
  part[t] = sum;
  __syncthreads();
  if (t == 0) {
    int run = 0;
    for (int i = 0; i < 256; ++i) { int v = part[i]; part[i] = run; run += v; }
  }
  __syncthreads();
  int run = part[t];
  for (int i = 0; i < CH; ++i) {
    int idx = base + i;
    if (idx < N_NODES_C) {
      int c = cnt[idx];
      dstart[idx] = run;
      dcur[idx] = run;  // overwrite with cursor
      run += c;
    }
  }
  if (t == 0) dstart[N_NODES_C] = N_EDGES_C;
}

// ---- bucket edges by dst; store packed (src | rel<<16, norm) as int2 ----
__global__ void bucket_dst_kernel(const int* __restrict__ dst, const int* __restrict__ src,
                                  const int* __restrict__ rel, const float* __restrict__ norm,
                                  int* __restrict__ dcur, int2* __restrict__ bkt) {
  int e = blockIdx.x * blockDim.x + threadIdx.x;
  if (e < N_EDGES_C) {
    int pos = atomicAdd(&dcur[dst[e]], 1);
    int2 pk;
    pk.x = src[e] | (rel[e] << 16);
    pk.y = __float_as_int(norm[e]);
    bkt[pos] = pk;
  }
}

// ---- Phase A: dense T[r][n][:] = hB[n,:] @ Wt[r]^T, stored bf16 in permuted col order ----
// Block mapping: blockIdx.x = m_tile*16 + r  (relation is the FASTEST dim so the 16
// blocks sharing an hB m-tile are co-resident -> hB fetched from HBM once, not 16x).
// Permutation: value for col (n0 + wn + nt2*16 + lr) is stored at (n0 + wn + lr*4 + nt2).
__global__ __launch_bounds__(256) void gemm_t_kernel(
    const bf16_t* __restrict__ hB, const bf16_t* __restrict__ Wt,
    bf16_t* __restrict__ Tb) {
  int bx = blockIdx.x;
  int r  = bx & 15;
  int m0 = (bx >> 4) << 7;
  int n0 = blockIdx.y * 128;

  __shared__ bf16_t Asm[128 * 32];   // 8 KB
  __shared__ bf16_t Bsm[128 * 32];   // 8 KB

  int tid = threadIdx.x;
  int lrow = tid >> 2;
  int pch = tid & 3;
  int rA0 = lrow, rA1 = lrow + 64;
  int lc0 = pch ^ ((rA0 >> 1) & 3);
  int lc1 = pch ^ ((rA1 >> 1) & 3);
  int gr0 = m0 + rA0; if (gr0 > N_NODES_C - 1) gr0 = N_NODES_C - 1;
  int gr1 = m0 + rA1; if (gr1 > N_NODES_C - 1) gr1 = N_NODES_C - 1;
  const char* gA0 = (const char*)(hB + (size_t)gr0 * FEAT_C) + lc0 * 16;
  const char* gA1 = (const char*)(hB + (size_t)gr1 * FEAT_C) + lc1 * 16;
  const char* gB0 = (const char*)(Wt + ((size_t)r * 256 + n0 + rA0) * FEAT_C) + lc0 * 16;
  const char* gB1 = (const char*)(Wt + ((size_t)r * 256 + n0 + rA1) * FEAT_C) + lc1 * 16;

  int wave = tid >> 6;
  char* aB0 = (char*)Asm + wave * 1024;
  char* aB1 = (char*)Asm + 4096 + wave * 1024;
  char* bB0 = (char*)Bsm + wave * 1024;
  char* bB1 = (char*)Bsm + 4096 + wave * 1024;

  int lane = tid & 63;
  int lq = lane >> 4;
  int lr = lane & 15;
  int wm = (wave >> 1) * 64;
  int wn = (wave & 1) * 64;
  int pc8 = (lq ^ ((lr >> 1) & 3)) * 8;

  f32x4 acc[4][4] = {};

  for (int kk = 0; kk < 8; ++kk) {
    int kb = kk * 64;
    async_load16(gA0 + kb, aB0);
    async_load16(gA1 + kb, aB1);
    async_load16(gB0 + kb, bB0);
    async_load16(gB1 + kb, bB1);
    __syncthreads();
    bf16x8 af[4], bfr[4];
#pragma unroll
    for (int mt = 0; mt < 4; ++mt) {
      int row = wm + mt * 16 + lr;
      af[mt] = *(const bf16x8*)&Asm[row * 32 + pc8];
    }
#pragma unroll
    for (int nt2 = 0; nt2 < 4; ++nt2) {
      int row = wn + nt2 * 16 + lr;
      bfr[nt2] = *(const bf16x8*)&Bsm[row * 32 + pc8];
    }
#pragma unroll
    for (int mt = 0; mt < 4; ++mt)
#pragma unroll
      for (int nt2 = 0; nt2 < 4; ++nt2)
        acc[mt][nt2] = __builtin_amdgcn_mfma_f32_16x16x32_bf16(af[mt], bfr[nt2], acc[mt][nt2], 0, 0, 0);
    __syncthreads();
  }

  // Epilogue: C/D map col=lane&15, row=quad*4+reg. Pack 4 cols (nt2=0..3, stride 16)
  // into one 8B store at permuted position n0+wn+lr*4.
#pragma unroll
  for (int mt = 0; mt < 4; ++mt) {
#pragma unroll
    for (int rg = 0; rg < 4; ++rg) {
      int row = m0 + wm + mt * 16 + lq * 4 + rg;
      if (row < N_NODES_C) {
        bf16x4 pk = { (bf16_t)acc[mt][0][rg], (bf16_t)acc[mt][1][rg],
                      (bf16_t)acc[mt][2][rg], (bf16_t)acc[mt][3][rg] };
        *(bf16x4*)(Tb + (((size_t)r * N_NODES_C + row) << 8) + n0 + wn + (lr << 2)) = pk;
      }
    }
  }
}

// ---- Phase B: per-dst gather-reduce over CSR, one wave per dst ----
__global__ __launch_bounds__(256) void aggregate_kernel(
    const bf16_t* __restrict__ Tb, const int* __restrict__ dstart,
    const int2* __restrict__ bkt, float* __restrict__ out) {
  int tid = threadIdx.x;
  int d = blockIdx.x * 4 + (tid >> 6);
  int lane = tid & 63;
  int p0 = dstart[d];
  int p1 = dstart[d + 1];
  float a0 = 0.f, a1 = 0.f, a2 = 0.f, a3 = 0.f;
  int loff = lane << 2;  // permuted positions 4l..4l+3
  int p = p0;
  // Unroll x2: keep two 512B gathers in flight.
  for (; p + 2 <= p1; p += 2) {
    int2 e0 = bkt[p];
    int2 e1 = bkt[p + 1];
    int s0 = e0.x & 0xFFFF, r0 = e0.x >> 16;
    int s1 = e1.x & 0xFFFF, r1 = e1.x >> 16;
    bf16x4 v0 = *(const bf16x4*)(Tb + (((size_t)r0 * N_NODES_C + s0) << 8) + loff);
    bf16x4 v1 = *(const bf16x4*)(Tb + (((size_t)r1 * N_NODES_C + s1) << 8) + loff);
    float n0 = __int_as_float(e0.y);
    float n1 = __int_as_float(e1.y);
    a0 += (float)v0[0] * n0 + (float)v1[0] * n1;
    a1 += (float)v0[1] * n0 + (float)v1[1] * n1;
    a2 += (float)v0[2] * n0 + (float)v1[2] * n1;
    a3 += (float)v0[3] * n0 + (float)v1[3] * n1;
  }
  if (p < p1) {
    int2 e0 = bkt[p];
    int s0 = e0.x & 0xFFFF, r0 = e0.x >> 16;
    bf16x4 v0 = *(const bf16x4*)(Tb + (((size_t)r0 * N_NODES_C + s0) << 8) + loff);
    float n0 = __int_as_float(e0.y);
    a0 += (float)v0[0] * n0;
    a1 += (float)v0[1] * n0;
    a2 += (float)v0[2] * n0;
    a3 += (float)v0[3] * n0;
  }
  // De-permute: position 4l+j holds col (4l&192) + j*16 + (l&15)
  float* o = out + (size_t)d * FEAT_C + ((lane << 2) & 192) + (lane & 15);
  o[0]  = a0;
  o[16] = a1;
  o[32] = a2;
  o[48] = a3;
}

extern "C" void kernel_launch(void* const* d_in, const int* in_sizes, int n_in,
                              void* d_out, int out_size, void* d_ws, size_t ws_size,
                              hipStream_t stream) {
  const float* h    = (const float*)d_in[0];
  const float* W    = (const float*)d_in[1];
  const float* norm = (const float*)d_in[2];
  const int*   src  = (const int*)d_in[3];
  const int*   dst  = (const int*)d_in[4];
  const int*   rel  = (const int*)d_in[5];
  float* out = (float*)d_out;

  char* ws = (char*)d_ws;
  bf16_t* hB   = (bf16_t*)ws;                          // 10,240,000 B
  bf16_t* Wt   = (bf16_t*)(ws + 10240000);             //  2,097,152 B
  bf16_t* Tb   = (bf16_t*)(ws + 12337152);             // 163,840,000 B
  int* dstart  = (int*)(ws + 176177152);               // 80,016 B (20001 ints)
  int* dcur    = (int*)(ws + 176257168);               // 80,000 B
  int2* bkt    = (int2*)(ws + 176337168);              // 2,560,000 B -> end ~178.9 MB

  hipMemsetAsync(dcur, 0, N_NODES_C * sizeof(int), stream);
  cvt_h_kernel<<<5000, 256, 0, stream>>>(h, hB);
  cvt_w_kernel<<<4096, 256, 0, stream>>>(W, Wt);
  hist_dst_kernel<<<1250, 256, 0, stream>>>(dst, dcur);
  scan_dst_kernel<<<1, 256, 0, stream>>>(dcur, dstart);
  bucket_dst_kernel<<<1250, 256, 0, stream>>>(dst, src, rel, norm, dcur, bkt);
  gemm_t_kernel<<<dim3(157 * 16, 2, 1), 256, 0, stream>>>(hB, Wt, Tb);
  aggregate_kernel<<<5000, 256, 0, stream>>>(Tb, dstart, bkt, out);
}

// Round 2
// 249.980 us; speedup vs baseline: 1.2247x; 1.0302x over previous
//
#include <hip/hip_runtime.h>
#include <stdint.h>

#define N_NODES_C 20000
#define N_EDGES_C 320000
#define NUM_RELS_C 16
#define FEAT_C 256

typedef __bf16 bf16_t;
typedef __bf16 bf16x8 __attribute__((ext_vector_type(8)));
typedef __bf16 bf16x4 __attribute__((ext_vector_type(4)));
typedef float f32x4 __attribute__((ext_vector_type(4)));

__device__ __forceinline__ void async_load16(const void* g, void* l) {
  __builtin_amdgcn_global_load_lds(
      (__attribute__((address_space(1))) void*)const_cast<void*>(g),
      (__attribute__((address_space(3))) void*)l, 16, 0, 0);
}

// ---- fused prep: [0,5000) h->bf16, [5000,9096) W transpose->bf16, [9096,10346) dst hist ----
__global__ void prep_kernel(const float* __restrict__ h, bf16_t* __restrict__ hB,
                            const float* __restrict__ W, bf16_t* __restrict__ Wt,
                            const int* __restrict__ dst, int* __restrict__ dcur) {
  int b = blockIdx.x;
  int t = threadIdx.x;
  if (b < 5000) {
    int i = (b * 256 + t) * 4;
    float4 v = *(const float4*)(h + i);
    bf16x4 o = { (bf16_t)v.x, (bf16_t)v.y, (bf16_t)v.z, (bf16_t)v.w };
    *(bf16x4*)(hB + i) = o;
  } else if (b < 9096) {
    int g = (b - 5000) * 256 + t;
    int i = g & 255;
    int o = (g >> 8) & 255;
    int r = g >> 16;
    Wt[(r << 16) + (o << 8) + i] = (bf16_t)W[(r << 16) + (i << 8) + o];
  } else {
    int e = (b - 9096) * 256 + t;
    if (e < N_EDGES_C) atomicAdd(&dcur[dst[e]], 1);
  }
}

// ---- single-block exclusive scan over 20000 counts -> dstart[20001], dcur=start cursors ----
// Counts staged in LDS (u16) so pass 2's run+=c chain is LDS-local.
__global__ void scan_dst_kernel(int* __restrict__ dcur, int* __restrict__ dstart) {
  __shared__ unsigned short cnt[20224];  // 256*79, 40.4 KB
  __shared__ int part[256];
  const int CH = 79;  // 256*79 = 20224 >= 20000
  int t = threadIdx.x;
  int base = t * CH;
  int sum = 0;
  for (int i = 0; i < CH; ++i) {
    int idx = base + i;
    int c = (idx < N_NODES_C) ? dcur[idx] : 0;
    cnt[idx] = (unsigned short)c;
    sum += c;
  }
  part[t] = sum;
  __syncthreads();
  if (t == 0) {
    int run = 0;
    for (int i = 0; i < 256; ++i) { int v = part[i]; part[i] = run; run += v; }
  }
  __syncthreads();
  int run = part[t];
  for (int i = 0; i < CH; ++i) {
    int idx = base + i;
    if (idx < N_NODES_C) {
      int c = cnt[idx];
      dstart[idx] = run;
      dcur[idx] = run;  // overwrite with cursor
      run += c;
    }
  }
  if (t == 0) dstart[N_NODES_C] = N_EDGES_C;
}

// ---- bucket edges by dst; store packed (src | rel<<16, norm) as int2 ----
__global__ void bucket_dst_kernel(const int* __restrict__ dst, const int* __restrict__ src,
                                  const int* __restrict__ rel, const float* __restrict__ norm,
                                  int* __restrict__ dcur, int2* __restrict__ bkt) {
  int e = blockIdx.x * blockDim.x + threadIdx.x;
  if (e < N_EDGES_C) {
    int pos = atomicAdd(&dcur[dst[e]], 1);
    int2 pk;
    pk.x = src[e] | (rel[e] << 16);
    pk.y = __float_as_int(norm[e]);
    bkt[pos] = pk;
  }
}

// ---- Phase A: dense T[r][n][:] = hB[n,:] @ Wt[r]^T, stored bf16 in permuted col order ----
// Block mapping: bx = m_tile*32 + r*2 + n_half -> ALL 32 blocks sharing an hB m-tile are
// adjacent in dispatch order (hB fetched from HBM once; Wt is LLC-resident).
// 2-phase pipeline: stage tile k+1 into dbuf BEFORE ds_read+MFMA of tile k; single
// barrier per iteration (its vmcnt(0)/lgkmcnt(0) drain provides both handoffs).
// Permutation: value for col (n0 + wn + nt2*16 + lr) is stored at (n0 + wn + lr*4 + nt2).
__global__ __launch_bounds__(256) void gemm_t_kernel(
    const bf16_t* __restrict__ hB, const bf16_t* __restrict__ Wt,
    bf16_t* __restrict__ Tb) {
  int bx = blockIdx.x;
  int sub = bx & 31;
  int m0 = (bx >> 5) << 7;
  int r  = sub >> 1;
  int n0 = (sub & 1) << 7;

  __shared__ bf16_t Asm[2 * 128 * 32];   // 16 KB (double-buffered)
  __shared__ bf16_t Bsm[2 * 128 * 32];   // 16 KB

  int tid = threadIdx.x;
  int lrow = tid >> 2;
  int pch = tid & 3;
  int rA0 = lrow, rA1 = lrow + 64;
  int lc0 = pch ^ ((rA0 >> 1) & 3);
  int lc1 = pch ^ ((rA1 >> 1) & 3);
  int gr0 = m0 + rA0; if (gr0 > N_NODES_C - 1) gr0 = N_NODES_C - 1;
  int gr1 = m0 + rA1; if (gr1 > N_NODES_C - 1) gr1 = N_NODES_C - 1;
  const char* gA0 = (const char*)(hB + (size_t)gr0 * FEAT_C) + lc0 * 16;
  const char* gA1 = (const char*)(hB + (size_t)gr1 * FEAT_C) + lc1 * 16;
  const char* gB0 = (const char*)(Wt + ((size_t)r * 256 + n0 + rA0) * FEAT_C) + lc0 * 16;
  const char* gB1 = (const char*)(Wt + ((size_t)r * 256 + n0 + rA1) * FEAT_C) + lc1 * 16;

  int wave = tid >> 6;
  char* aL = (char*)Asm + wave * 1024;
  char* bL = (char*)Bsm + wave * 1024;

  int lane = tid & 63;
  int lq = lane >> 4;
  int lr = lane & 15;
  int wm = (wave >> 1) * 64;
  int wn = (wave & 1) * 64;
  int pc8 = (lq ^ ((lr >> 1) & 3)) * 8;

  f32x4 acc[4][4] = {};

  // prologue: stage tile 0 into buf 0
  async_load16(gA0, aL);
  async_load16(gA1, aL + 4096);
  async_load16(gB0, bL);
  async_load16(gB1, bL + 4096);
  __syncthreads();

  for (int kk = 0; kk < 8; ++kk) {
    int cur = kk & 1;
    if (kk < 7) {
      int kb = (kk + 1) * 64;
      int nxt = cur ^ 1;
      async_load16(gA0 + kb, aL + nxt * 8192);
      async_load16(gA1 + kb, aL + nxt * 8192 + 4096);
      async_load16(gB0 + kb, bL + nxt * 8192);
      async_load16(gB1 + kb, bL + nxt * 8192 + 4096);
    }
    const bf16_t* Ac = Asm + cur * 4096;
    const bf16_t* Bc = Bsm + cur * 4096;
    bf16x8 af[4], bfr[4];
#pragma unroll
    for (int mt = 0; mt < 4; ++mt) {
      int row = wm + mt * 16 + lr;
      af[mt] = *(const bf16x8*)&Ac[row * 32 + pc8];
    }
#pragma unroll
    for (int nt2 = 0; nt2 < 4; ++nt2) {
      int row = wn + nt2 * 16 + lr;
      bfr[nt2] = *(const bf16x8*)&Bc[row * 32 + pc8];
    }
#pragma unroll
    for (int mt = 0; mt < 4; ++mt)
#pragma unroll
      for (int nt2 = 0; nt2 < 4; ++nt2)
        acc[mt][nt2] = __builtin_amdgcn_mfma_f32_16x16x32_bf16(af[mt], bfr[nt2], acc[mt][nt2], 0, 0, 0);
    __syncthreads();  // drains vmcnt (next tile staged) + lgkmcnt (this tile's ds_reads)
  }

  // Epilogue: C/D map col=lane&15, row=quad*4+reg. Pack 4 cols (nt2=0..3, stride 16)
  // into one 8B store at permuted position n0+wn+lr*4.
#pragma unroll
  for (int mt = 0; mt < 4; ++mt) {
#pragma unroll
    for (int rg = 0; rg < 4; ++rg) {
      int row = m0 + wm + mt * 16 + lq * 4 + rg;
      if (row < N_NODES_C) {
        bf16x4 pk = { (bf16_t)acc[mt][0][rg], (bf16_t)acc[mt][1][rg],
                      (bf16_t)acc[mt][2][rg], (bf16_t)acc[mt][3][rg] };
        *(bf16x4*)(Tb + (((size_t)r * N_NODES_C + row) << 8) + n0 + wn + (lr << 2)) = pk;
      }
    }
  }
}

// ---- Phase B: per-dst gather-reduce over CSR, one wave per dst ----
__global__ __launch_bounds__(256) void aggregate_kernel(
    const bf16_t* __restrict__ Tb, const int* __restrict__ dstart,
    const int2* __restrict__ bkt, float* __restrict__ out) {
  int tid = threadIdx.x;
  int d = blockIdx.x * 4 + (tid >> 6);
  int lane = tid & 63;
  int p0 = dstart[d];
  int p1 = dstart[d + 1];
  float a0 = 0.f, a1 = 0.f, a2 = 0.f, a3 = 0.f;
  int loff = lane << 2;  // permuted positions 4l..4l+3
  int p = p0;
  // Unroll x2: keep two 512B gathers in flight.
  for (; p + 2 <= p1; p += 2) {
    int2 e0 = bkt[p];
    int2 e1 = bkt[p + 1];
    int s0 = e0.x & 0xFFFF, r0 = e0.x >> 16;
    int s1 = e1.x & 0xFFFF, r1 = e1.x >> 16;
    bf16x4 v0 = *(const bf16x4*)(Tb + (((size_t)r0 * N_NODES_C + s0) << 8) + loff);
    bf16x4 v1 = *(const bf16x4*)(Tb + (((size_t)r1 * N_NODES_C + s1) << 8) + loff);
    float n0 = __int_as_float(e0.y);
    float n1 = __int_as_float(e1.y);
    a0 += (float)v0[0] * n0 + (float)v1[0] * n1;
    a1 += (float)v0[1] * n0 + (float)v1[1] * n1;
    a2 += (float)v0[2] * n0 + (float)v1[2] * n1;
    a3 += (float)v0[3] * n0 + (float)v1[3] * n1;
  }
  if (p < p1) {
    int2 e0 = bkt[p];
    int s0 = e0.x & 0xFFFF, r0 = e0.x >> 16;
    bf16x4 v0 = *(const bf16x4*)(Tb + (((size_t)r0 * N_NODES_C + s0) << 8) + loff);
    float n0 = __int_as_float(e0.y);
    a0 += (float)v0[0] * n0;
    a1 += (float)v0[1] * n0;
    a2 += (float)v0[2] * n0;
    a3 += (float)v0[3] * n0;
  }
  // De-permute: position 4l+j holds col (4l&192) + j*16 + (l&15)
  float* o = out + (size_t)d * FEAT_C + ((lane << 2) & 192) + (lane & 15);
  o[0]  = a0;
  o[16] = a1;
  o[32] = a2;
  o[48] = a3;
}

extern "C" void kernel_launch(void* const* d_in, const int* in_sizes, int n_in,
                              void* d_out, int out_size, void* d_ws, size_t ws_size,
                              hipStream_t stream) {
  const float* h    = (const float*)d_in[0];
  const float* W    = (const float*)d_in[1];
  const float* norm = (const float*)d_in[2];
  const int*   src  = (const int*)d_in[3];
  const int*   dst  = (const int*)d_in[4];
  const int*   rel  = (const int*)d_in[5];
  float* out = (float*)d_out;

  char* ws = (char*)d_ws;
  bf16_t* hB   = (bf16_t*)ws;                          // 10,240,000 B
  bf16_t* Wt   = (bf16_t*)(ws + 10240000);             //  2,097,152 B
  bf16_t* Tb   = (bf16_t*)(ws + 12337152);             // 163,840,000 B
  int* dstart  = (int*)(ws + 176177152);               // 80,016 B (20001 ints)
  int* dcur    = (int*)(ws + 176257168);               // 80,000 B
  int2* bkt    = (int2*)(ws + 176337168);              // 2,560,000 B -> end ~178.9 MB

  hipMemsetAsync(dcur, 0, N_NODES_C * sizeof(int), stream);
  prep_kernel<<<10346, 256, 0, stream>>>(h, hB, W, Wt, dst, dcur);
  scan_dst_kernel<<<1, 256, 0, stream>>>(dcur, dstart);
  bucket_dst_kernel<<<1250, 256, 0, stream>>>(dst, src, rel, norm, dcur, bkt);
  gemm_t_kernel<<<dim3(157 * 32, 1, 1), 256, 0, stream>>>(hB, Wt, Tb);
  aggregate_kernel<<<5000, 256, 0, stream>>>(Tb, dstart, bkt, out);
}